// Round 3
// baseline (747.337 us; speedup 1.0000x reference)
//
#include <hip/hip_runtime.h>

// ---------------------------------------------------------------------------
// SlidingWindowSelfAttention on MI355X (gfx950), bf16 MFMA pipeline:
//   cast(x,wqkv,wout) -> GEMM1 qkv (Q scaled, V written transposed)
//   -> flash attention (S^T = K Q^T formulation) -> GEMM2 out (fp32)
// R3: phase-swizzled block mapping (per-XCD A footprint 4MB->2MB, L2-resident)
//     + nontemporal epilogue stores (write stream no longer evicts A from L2).
//     Theory: R1/R2 were L2-miss-bandwidth-bound (~7.5 TB/s demand on L3 path),
//     not latency-bound — m97 sustains 12.7 TB/s when A-rereads are L2 hits.
// ---------------------------------------------------------------------------

typedef __bf16 bf16x8 __attribute__((ext_vector_type(8)));
typedef float  f32x4  __attribute__((ext_vector_type(4)));
typedef unsigned short u16x4 __attribute__((ext_vector_type(4)));

#define MFMA(a, b, c) __builtin_amdgcn_mfma_f32_16x16x32_bf16(a, b, c, 0, 0, 0)

__device__ __forceinline__ unsigned short f2bf(float f) {
  union { float f; unsigned u; } v; v.f = f;
  unsigned r = v.u + 0x7FFFu + ((v.u >> 16) & 1u);   // RNE
  return (unsigned short)(r >> 16);
}

// async global->LDS, 16B/lane; LDS dest = wave-uniform base + lane*16
__device__ __forceinline__ void gl16(const void* g, void* l) {
  __builtin_amdgcn_global_load_lds(
      (const __attribute__((address_space(1))) unsigned int*)g,
      (__attribute__((address_space(3))) unsigned int*)l, 16, 0, 0);
}

// ---------------------------------------------------------------------------
__global__ void cast_bf16(const float4* __restrict__ in,
                          u16x4* __restrict__ out, int n4) {
  int i = blockIdx.x * blockDim.x + threadIdx.x;
  if (i < n4) {
    float4 v = in[i];
    u16x4 o;
    o[0] = f2bf(v.x); o[1] = f2bf(v.y); o[2] = f2bf(v.z); o[3] = f2bf(v.w);
    out[i] = o;
  }
}

// ---------------------------------------------------------------------------
// C = A * B^T. A:[M,K] bf16 row-major, B:[N,K] bf16 row-major (torch weight).
// 128x128 tile, BK=32, 4 waves each 64x64. Frag-major LDS: ds_read_b128 is
// lane-linear (conflict-free). Double-buffered global_load_lds prefetch.
// 1D grid, phase-swizzled: gm must be 64. Phase covers bx in [0,32)+32*phase,
// so XCD = id%8 sees only 4 distinct A-row tiles (2 MB) concurrently -> A
// re-reads are L2 hits. Same-by blocks are dispatch-adjacent (B-tile shared).
// MODE 1: qkv epilogue (Q scaled 1/sqrt(D), V transposed into VT[B,H,D,S]).
// MODE 2: fp32 row-major C. All epilogue stores nontemporal.
template <int MODE>
__global__ __launch_bounds__(256, 2) void gemm_bt(
    const unsigned short* __restrict__ A, const unsigned short* __restrict__ Bw,
    void* __restrict__ C1, void* __restrict__ C2, int K, int gn, int Nstride) {
  __shared__ unsigned char sm[32768];  // 2 x (A frags 8KB | B frags 8KB)
  const int tid = threadIdx.x, lane = tid & 63, w = tid >> 6;
  const int l15 = lane & 15, lg = lane >> 4;

  // phase swizzle: id -> (bx, by); per-XCD concurrent A footprint = 4 tiles
  const int id = blockIdx.x;
  const int phs = gn << 5;                 // 32 * gn blocks per phase
  const int phase = id / phs;
  const int rem = id - phase * phs;
  const int bm = (((rem & 31) + (phase << 5))) * 128;
  const int bn = (rem >> 5) * 128;

  const int wm = (w & 1) * 4, wn = (w >> 1) * 4;  // 16-row/col band bases

  f32x4 acc[4][4] = {};

  // per-wave staging sources: wave w loads fragments f = w, w+4, w+8, w+12
  const unsigned short* srcA[2];  // f = w, w+4        (A bands, f in 0..7)
  const unsigned short* srcB[2];  // f = w+8, w+12     (B bands)
  srcA[0] = A + (size_t)(bm + w * 16 + l15) * K + lg * 8;
  srcA[1] = A + (size_t)(bm + (w + 4) * 16 + l15) * K + lg * 8;
  srcB[0] = Bw + (size_t)(bn + w * 16 + l15) * K + lg * 8;
  srcB[1] = Bw + (size_t)(bn + (w + 4) * 16 + l15) * K + lg * 8;

  // prologue: issue loads for k0 = 0 into buffer 0
  {
    unsigned char* buf = sm;
    gl16(srcA[0], buf + (w)*1024);
    gl16(srcA[1], buf + (w + 4) * 1024);
    gl16(srcB[0], buf + (w + 8) * 1024);
    gl16(srcB[1], buf + (w + 12) * 1024);
  }

  int p = 0;
  for (int k0 = 0; k0 < K; k0 += 32) {
    __syncthreads();  // drains vmcnt(0): buf[p] ready; buf[p^1] readers done
    unsigned char* cur = sm + p * 16384;
    if (k0 + 32 < K) {  // prefetch next K-slice into the other buffer
      unsigned char* nxt = sm + (p ^ 1) * 16384;
      int ko = k0 + 32;
      gl16(srcA[0] + ko, nxt + (w)*1024);
      gl16(srcA[1] + ko, nxt + (w + 4) * 1024);
      gl16(srcB[0] + ko, nxt + (w + 8) * 1024);
      gl16(srcB[1] + ko, nxt + (w + 12) * 1024);
    }
    bf16x8 af[4], bfr[4];
#pragma unroll
    for (int i = 0; i < 4; i++)
      af[i] = *(const bf16x8*)(cur + ((wm + i) * 64 + lane) * 16);
#pragma unroll
    for (int j = 0; j < 4; j++)
      bfr[j] = *(const bf16x8*)(cur + 8192 + ((wn + j) * 64 + lane) * 16);
#pragma unroll
    for (int i = 0; i < 4; i++)
#pragma unroll
      for (int j = 0; j < 4; j++)
        acc[i][j] = MFMA(af[i], bfr[j], acc[i][j]);
    p ^= 1;
  }

  // C/D layout: col n = lane&15, row m = (lane>>4)*4 + r  [m89/m91 verified]
  if (MODE == 1) {
    unsigned short* QK = (unsigned short*)C1;  // [8192][4096] = Q|K
    unsigned short* VT = (unsigned short*)C2;  // [2*16*128][4096]
    if (bn < 4096) {
      const float scl = (bn < 2048) ? 0.08838834764831845f : 1.0f;  // Q pre-scale
#pragma unroll
      for (int i = 0; i < 4; i++) {
        int m0 = bm + (wm + i) * 16 + lg * 4;
#pragma unroll
        for (int j = 0; j < 4; j++) {
          int n = bn + (wn + j) * 16 + l15;
#pragma unroll
          for (int r = 0; r < 4; r++)
            __builtin_nontemporal_store(f2bf(acc[i][j][r] * scl),
                                        &QK[(size_t)(m0 + r) * 4096 + n]);
        }
      }
    } else {  // V: 4 consecutive m = consecutive s in VT -> packed 8B store
#pragma unroll
      for (int i = 0; i < 4; i++) {
        int m0 = bm + (wm + i) * 16 + lg * 4;
        int bb = m0 >> 12, s = m0 & 4095;
#pragma unroll
        for (int j = 0; j < 4; j++) {
          int n4 = bn + (wn + j) * 16 + l15 - 4096;
          int hh = n4 >> 7, d = n4 & 127;
          u16x4 pk;
#pragma unroll
          for (int r = 0; r < 4; r++) pk[r] = f2bf(acc[i][j][r]);
          __builtin_nontemporal_store(
              pk, (u16x4*)(VT + ((size_t)((bb * 16 + hh) * 128 + d) * 4096 + s)));
        }
      }
    }
  } else {
    float* C = (float*)C1;
#pragma unroll
    for (int i = 0; i < 4; i++) {
      int m0 = bm + (wm + i) * 16 + lg * 4;
#pragma unroll
      for (int j = 0; j < 4; j++) {
        int n = bn + (wn + j) * 16 + l15;
#pragma unroll
        for (int r = 0; r < 4; r++)
          __builtin_nontemporal_store(acc[i][j][r],
                                      &C[(size_t)(m0 + r) * Nstride + n]);
      }
    }
  }
}

// ---------------------------------------------------------------------------
// Flash attention, S^T = K·Q^T formulation. Block = (b,h,128 queries),
// 4 waves x 32 queries. KV tiles of 64, span [q0-512, q0+128).
// C-layout col (lane&15) = query -> softmax reduces with 2 shuffles,
// P^T packs to ds_write_b64, O packs to 8B global stores.
__global__ __launch_bounds__(256, 2) void attn(
    const unsigned short* __restrict__ QK,  // [B*S][4096], Q pre-scaled
    const unsigned short* __restrict__ VT,  // [B*H*D][S]
    unsigned short* __restrict__ O) {       // [B*S][2048]
  __shared__ unsigned char sm[51200];
  // [0,16K): K frags [kvb4][ks4][lane]x16B   [16K,32K): V frags [db8][kvs2][lane]
  // [32K,50K): P^T per wave 4608B: [m 32][kv 64] bf16, row stride 144B
  const int tid = threadIdx.x, lane = tid & 63, w = tid >> 6;
  const int l15 = lane & 15, lg = lane >> 4;
  const int bid = blockIdx.x;
  const int qc = bid & 31, h = (bid >> 5) & 15, b = bid >> 9;
  const int q0 = qc * 128;

  // Q fragments (B-operand: lane&15 = query, lg*8 = d-chunk) direct to regs
  bf16x8 qf[2][4];
#pragma unroll
  for (int mb = 0; mb < 2; mb++) {
    const unsigned short* qrow =
        QK + (size_t)(b * 4096 + q0 + (2 * w + mb) * 16 + l15) * 4096 + h * 128 + lg * 8;
#pragma unroll
    for (int ks = 0; ks < 4; ks++) qf[mb][ks] = *(const bf16x8*)(qrow + ks * 32);
  }

  float mrun[2] = {-1e30f, -1e30f}, lrun[2] = {0.f, 0.f};
  f32x4 oacc[8][2] = {};  // O^T tiles [db][mb]: row=d, col=query

  const int t0 = (q0 < 512) ? (512 - q0) >> 6 : 0;  // skip kv<0 tiles
  unsigned char* Ps = sm + 32768 + w * 4608;

  for (int t = t0; t < 10; t++) {
    const int kv0 = q0 - 512 + t * 64;
    __syncthreads();
#pragma unroll
    for (int u = 0; u < 4; u++) {
      int f = w + u * 4;
      int kvb = f >> 2, ks = f & 3;
      gl16(QK + (size_t)(b * 4096 + kv0 + kvb * 16 + l15) * 4096 + 2048 + h * 128 + ks * 32 + lg * 8,
           sm + (kvb * 4 + ks) * 1024);
      int db = f >> 1, kvs = f & 1;
      gl16(VT + (size_t)((b * 16 + h) * 128 + db * 16 + l15) * 4096 + kv0 + kvs * 32 + lg * 8,
           sm + 16384 + (db * 2 + kvs) * 1024);
    }
    __syncthreads();

    // S^T tiles [kvb][mb]: D row = kv (lg*4+r), D col = query (l15)
    f32x4 sacc[4][2] = {};
#pragma unroll
    for (int ks = 0; ks < 4; ks++)
#pragma unroll
      for (int kvb = 0; kvb < 4; kvb++) {
        bf16x8 kf = *(const bf16x8*)(sm + (kvb * 4 + ks) * 1024 + lane * 16);
        sacc[kvb][0] = MFMA(kf, qf[0][ks], sacc[kvb][0]);
        sacc[kvb][1] = MFMA(kf, qf[1][ks], sacc[kvb][1]);
      }

    if (t <= 1 || t >= 8) {  // only window-edge / causal-edge tiles need masks
#pragma unroll
      for (int kvb = 0; kvb < 4; kvb++)
#pragma unroll
        for (int mb = 0; mb < 2; mb++) {
          int qg = q0 + w * 32 + mb * 16 + l15;
          int kgb = kv0 + kvb * 16 + lg * 4;
#pragma unroll
          for (int r = 0; r < 4; r++) {
            int diff = qg - (kgb + r);
            if (diff < 0 || diff > 512) sacc[kvb][mb][r] = -1e30f;
          }
        }
    }

#pragma unroll
    for (int mb = 0; mb < 2; mb++) {
      float tmax = -1e30f;
#pragma unroll
      for (int kvb = 0; kvb < 4; kvb++)
#pragma unroll
        for (int r = 0; r < 4; r++) tmax = fmaxf(tmax, sacc[kvb][mb][r]);
      tmax = fmaxf(tmax, __shfl_xor(tmax, 16));
      tmax = fmaxf(tmax, __shfl_xor(tmax, 32));
      float mnew = fmaxf(mrun[mb], tmax);
      float alpha = __expf(mrun[mb] - mnew);
      mrun[mb] = mnew;
      float lsum = 0.f;
#pragma unroll
      for (int kvb = 0; kvb < 4; kvb++) {
        u16x4 pk;
#pragma unroll
        for (int r = 0; r < 4; r++) {
          float p = __expf(sacc[kvb][mb][r] - mnew);
          lsum += p;
          pk[r] = f2bf(p);
        }
        *(u16x4*)(Ps + (mb * 16 + l15) * 144 + kvb * 32 + lg * 8) = pk;
      }
      lsum += __shfl_xor(lsum, 16);
      lsum += __shfl_xor(lsum, 32);
      lrun[mb] = lrun[mb] * alpha + lsum;
#pragma unroll
      for (int db = 0; db < 8; db++)
#pragma unroll
        for (int r = 0; r < 4; r++) oacc[db][mb][r] *= alpha;
    }

    // O^T += V^T · P^T  (A = V^T frag, lane-linear; B = P^T, contiguous b128)
#pragma unroll
    for (int kvs = 0; kvs < 2; kvs++) {
      bf16x8 pf0 = *(const bf16x8*)(Ps + (0 + l15) * 144 + kvs * 64 + lg * 16);
      bf16x8 pf1 = *(const bf16x8*)(Ps + (16 + l15) * 144 + kvs * 64 + lg * 16);
#pragma unroll
      for (int db = 0; db < 8; db++) {
        bf16x8 vf = *(const bf16x8*)(sm + 16384 + (db * 2 + kvs) * 1024 + lane * 16);
        oacc[db][0] = MFMA(vf, pf0, oacc[db][0]);
        oacc[db][1] = MFMA(vf, pf1, oacc[db][1]);
      }
    }
  }

#pragma unroll
  for (int mb = 0; mb < 2; mb++) {
    float inv = 1.0f / lrun[mb];
    int s = q0 + w * 32 + mb * 16 + l15;
    unsigned short* orow = O + (size_t)(b * 4096 + s) * 2048 + h * 128 + lg * 4;
#pragma unroll
    for (int db = 0; db < 8; db++) {
      u16x4 pk;
#pragma unroll
      for (int r = 0; r < 4; r++) pk[r] = f2bf(oacc[db][mb][r] * inv);
      *(u16x4*)(orow + db * 16) = pk;
    }
  }
}

// ---------------------------------------------------------------------------
extern "C" void kernel_launch(void* const* d_in, const int* in_sizes, int n_in,
                              void* d_out, int out_size, void* d_ws, size_t ws_size,
                              hipStream_t stream) {
  const float* x = (const float*)d_in[0];       // [2,4096,2048]
  const float* w_qkv = (const float*)d_in[1];   // [6144,2048]
  const float* w_out = (const float*)d_in[2];   // [2048,2048]
  float* out = (float*)d_out;                   // [2,4096,2048] fp32

  char* ws = (char*)d_ws;
  unsigned short* XB    = (unsigned short*)(ws);                         // 32M
  unsigned short* WQKVB = (unsigned short*)(ws + 33554432);              // 24M
  unsigned short* WOUTB = (unsigned short*)(ws + 58720256);              // 8M
  unsigned short* QKb   = (unsigned short*)(ws + 67108864);              // 64M
  unsigned short* VTb   = (unsigned short*)(ws + 134217728);             // 32M
  unsigned short* OB    = XB;  // XB dead after GEMM1; reuse for attention output
  // total workspace: 160 MiB

  cast_bf16<<<16384, 256, 0, stream>>>((const float4*)x, (u16x4*)XB, 4194304);
  cast_bf16<<<12288, 256, 0, stream>>>((const float4*)w_qkv, (u16x4*)WQKVB, 3145728);
  cast_bf16<<<4096, 256, 0, stream>>>((const float4*)w_out, (u16x4*)WOUTB, 1048576);

  // qkv = x @ w_qkv^T : M=8192, N=6144, K=2048 ; grid 64x48 phase-swizzled
  gemm_bt<1><<<3072, 256, 0, stream>>>(XB, WQKVB, QKb, VTb, 2048, 48, 0);

  // sliding-window attention: grid = B*H*(S/128)
  attn<<<1024, 256, 0, stream>>>(QKb, VTb, OB);

  // out = o @ w_out^T : M=8192, N=2048, K=2048 ; grid 64x16 phase-swizzled
  gemm_bt<2><<<1024, 256, 0, stream>>>(OB, WOUTB, out, nullptr, 2048, 16, 2048);
}

// Round 4
// 617.704 us; speedup vs baseline: 1.2099x; 1.2099x over previous
//
#include <hip/hip_runtime.h>

// ---------------------------------------------------------------------------
// SlidingWindowSelfAttention on MI355X (gfx950), bf16 MFMA pipeline:
//   cast(x,wqkv,wout) -> GEMM1 qkv (Q scaled, V written transposed)
//   -> flash attention (S^T = K Q^T formulation) -> GEMM2 out (fp32)
// R4: 256x128 tile, 512 threads / 8 waves (each wave 64x64, same proven
//     microstructure). Theory: R1-R3 were service-BW bound at ~7.4 TB/s with
//     intensity 64 FLOP/B (=509 TF); 256x128 raises intensity to 85 and halves
//     per-XCD block concurrency so the K-window footprint fits L2.
//     Nontemporal stores reverted (R3: doubled WRITE_SIZE, no dur change).
// ---------------------------------------------------------------------------

typedef __bf16 bf16x8 __attribute__((ext_vector_type(8)));
typedef float  f32x4  __attribute__((ext_vector_type(4)));
typedef unsigned short u16x4 __attribute__((ext_vector_type(4)));

#define MFMA(a, b, c) __builtin_amdgcn_mfma_f32_16x16x32_bf16(a, b, c, 0, 0, 0)

__device__ __forceinline__ unsigned short f2bf(float f) {
  union { float f; unsigned u; } v; v.f = f;
  unsigned r = v.u + 0x7FFFu + ((v.u >> 16) & 1u);   // RNE
  return (unsigned short)(r >> 16);
}

// async global->LDS, 16B/lane; LDS dest = wave-uniform base + lane*16
__device__ __forceinline__ void gl16(const void* g, void* l) {
  __builtin_amdgcn_global_load_lds(
      (const __attribute__((address_space(1))) unsigned int*)g,
      (__attribute__((address_space(3))) unsigned int*)l, 16, 0, 0);
}

// ---------------------------------------------------------------------------
__global__ void cast_bf16(const float4* __restrict__ in,
                          u16x4* __restrict__ out, int n4) {
  int i = blockIdx.x * blockDim.x + threadIdx.x;
  if (i < n4) {
    float4 v = in[i];
    u16x4 o;
    o[0] = f2bf(v.x); o[1] = f2bf(v.y); o[2] = f2bf(v.z); o[3] = f2bf(v.w);
    out[i] = o;
  }
}

// ---------------------------------------------------------------------------
// C = A * B^T. A:[M,K] bf16 row-major, B:[N,K] bf16 row-major (torch weight).
// 256x128 tile, BK=32, 8 waves each 64x64. Frag-major LDS: ds_read_b128 is
// lane-linear (conflict-free). Double-buffered global_load_lds prefetch.
// A frags f in [0,16) at f*1024; B frags g in [0,8) at 16384+g*1024.
// Buffer stride 24576, LDS total 48 KB -> 2 blocks/CU (96 KB).
// MODE 1: qkv epilogue (Q scaled 1/sqrt(D), V transposed into VT[B,H,D,S]).
// MODE 2: fp32 row-major C.
template <int MODE>
__global__ __launch_bounds__(512, 4) void gemm_bt(
    const unsigned short* __restrict__ A, const unsigned short* __restrict__ Bw,
    void* __restrict__ C1, void* __restrict__ C2, int K, int Nstride) {
  __shared__ unsigned char sm[49152];  // 2 x (A frags 16KB | B frags 8KB)
  const int tid = threadIdx.x, lane = tid & 63, w = tid >> 6;   // 8 waves
  const int l15 = lane & 15, lg = lane >> 4;
  const int bm = blockIdx.x * 256, bn = blockIdx.y * 128;
  const int wmt = (w & 3) * 4, wnt = (w >> 2) * 4;  // band bases in 16-tile units

  f32x4 acc[4][4] = {};

  // per-wave staging: wave w loads A-frags {w, w+8} and B-frag {w}
  const unsigned short* srcA0 = A + (size_t)(bm + w * 16 + l15) * K + lg * 8;
  const unsigned short* srcA1 = A + (size_t)(bm + (w + 8) * 16 + l15) * K + lg * 8;
  const unsigned short* srcB0 = Bw + (size_t)(bn + w * 16 + l15) * K + lg * 8;

  // prologue: issue loads for k0 = 0 into buffer 0
  gl16(srcA0, sm + w * 1024);
  gl16(srcA1, sm + (w + 8) * 1024);
  gl16(srcB0, sm + 16384 + w * 1024);

  int p = 0;
  for (int k0 = 0; k0 < K; k0 += 32) {
    __syncthreads();  // drains vmcnt(0): buf[p] ready; buf[p^1] readers done
    unsigned char* cur = sm + p * 24576;
    if (k0 + 32 < K) {  // prefetch next K-slice into the other buffer
      unsigned char* nxt = sm + (p ^ 1) * 24576;
      int ko = k0 + 32;
      gl16(srcA0 + ko, nxt + w * 1024);
      gl16(srcA1 + ko, nxt + (w + 8) * 1024);
      gl16(srcB0 + ko, nxt + 16384 + w * 1024);
    }
    bf16x8 af[4], bfr[4];
#pragma unroll
    for (int i = 0; i < 4; i++)
      af[i] = *(const bf16x8*)(cur + ((wmt + i) * 64 + lane) * 16);
#pragma unroll
    for (int j = 0; j < 4; j++)
      bfr[j] = *(const bf16x8*)(cur + 16384 + ((wnt + j) * 64 + lane) * 16);
#pragma unroll
    for (int i = 0; i < 4; i++)
#pragma unroll
      for (int j = 0; j < 4; j++)
        acc[i][j] = MFMA(af[i], bfr[j], acc[i][j]);
    p ^= 1;
  }

  // C/D layout: col n = lane&15, row m = (lane>>4)*4 + r  [m89/m91 verified]
  if (MODE == 1) {
    unsigned short* QK = (unsigned short*)C1;  // [8192][4096] = Q|K
    unsigned short* VT = (unsigned short*)C2;  // [2*16*128][4096]
    if (bn < 4096) {
      const float scl = (bn < 2048) ? 0.08838834764831845f : 1.0f;  // Q pre-scale
#pragma unroll
      for (int i = 0; i < 4; i++) {
        int m0 = bm + (wmt + i) * 16 + lg * 4;
#pragma unroll
        for (int j = 0; j < 4; j++) {
          int n = bn + (wnt + j) * 16 + l15;
#pragma unroll
          for (int r = 0; r < 4; r++)
            QK[(size_t)(m0 + r) * 4096 + n] = f2bf(acc[i][j][r] * scl);
        }
      }
    } else {  // V: 4 consecutive m = consecutive s in VT -> packed 8B store
#pragma unroll
      for (int i = 0; i < 4; i++) {
        int m0 = bm + (wmt + i) * 16 + lg * 4;
        int bb = m0 >> 12, s = m0 & 4095;
#pragma unroll
        for (int j = 0; j < 4; j++) {
          int n4 = bn + (wnt + j) * 16 + l15 - 4096;
          int hh = n4 >> 7, d = n4 & 127;
          u16x4 pk;
#pragma unroll
          for (int r = 0; r < 4; r++) pk[r] = f2bf(acc[i][j][r]);
          *(u16x4*)(VT + ((size_t)((bb * 16 + hh) * 128 + d) * 4096 + s)) = pk;
        }
      }
    }
  } else {
    float* C = (float*)C1;
#pragma unroll
    for (int i = 0; i < 4; i++) {
      int m0 = bm + (wmt + i) * 16 + lg * 4;
#pragma unroll
      for (int j = 0; j < 4; j++) {
        int n = bn + (wnt + j) * 16 + l15;
#pragma unroll
        for (int r = 0; r < 4; r++)
          C[(size_t)(m0 + r) * Nstride + n] = acc[i][j][r];
      }
    }
  }
}

// ---------------------------------------------------------------------------
// Flash attention, S^T = K·Q^T formulation. Block = (b,h,128 queries),
// 4 waves x 32 queries. KV tiles of 64, span [q0-512, q0+128).
// C-layout col (lane&15) = query -> softmax reduces with 2 shuffles,
// P^T packs to ds_write_b64, O packs to 8B global stores.
__global__ __launch_bounds__(256, 2) void attn(
    const unsigned short* __restrict__ QK,  // [B*S][4096], Q pre-scaled
    const unsigned short* __restrict__ VT,  // [B*H*D][S]
    unsigned short* __restrict__ O) {       // [B*S][2048]
  __shared__ unsigned char sm[51200];
  // [0,16K): K frags [kvb4][ks4][lane]x16B   [16K,32K): V frags [db8][kvs2][lane]
  // [32K,50K): P^T per wave 4608B: [m 32][kv 64] bf16, row stride 144B
  const int tid = threadIdx.x, lane = tid & 63, w = tid >> 6;
  const int l15 = lane & 15, lg = lane >> 4;
  const int bid = blockIdx.x;
  const int qc = bid & 31, h = (bid >> 5) & 15, b = bid >> 9;
  const int q0 = qc * 128;

  // Q fragments (B-operand: lane&15 = query, lg*8 = d-chunk) direct to regs
  bf16x8 qf[2][4];
#pragma unroll
  for (int mb = 0; mb < 2; mb++) {
    const unsigned short* qrow =
        QK + (size_t)(b * 4096 + q0 + (2 * w + mb) * 16 + l15) * 4096 + h * 128 + lg * 8;
#pragma unroll
    for (int ks = 0; ks < 4; ks++) qf[mb][ks] = *(const bf16x8*)(qrow + ks * 32);
  }

  float mrun[2] = {-1e30f, -1e30f}, lrun[2] = {0.f, 0.f};
  f32x4 oacc[8][2] = {};  // O^T tiles [db][mb]: row=d, col=query

  const int t0 = (q0 < 512) ? (512 - q0) >> 6 : 0;  // skip kv<0 tiles
  unsigned char* Ps = sm + 32768 + w * 4608;

  for (int t = t0; t < 10; t++) {
    const int kv0 = q0 - 512 + t * 64;
    __syncthreads();
#pragma unroll
    for (int u = 0; u < 4; u++) {
      int f = w + u * 4;
      int kvb = f >> 2, ks = f & 3;
      gl16(QK + (size_t)(b * 4096 + kv0 + kvb * 16 + l15) * 4096 + 2048 + h * 128 + ks * 32 + lg * 8,
           sm + (kvb * 4 + ks) * 1024);
      int db = f >> 1, kvs = f & 1;
      gl16(VT + (size_t)((b * 16 + h) * 128 + db * 16 + l15) * 4096 + kv0 + kvs * 32 + lg * 8,
           sm + 16384 + (db * 2 + kvs) * 1024);
    }
    __syncthreads();

    // S^T tiles [kvb][mb]: D row = kv (lg*4+r), D col = query (l15)
    f32x4 sacc[4][2] = {};
#pragma unroll
    for (int ks = 0; ks < 4; ks++)
#pragma unroll
      for (int kvb = 0; kvb < 4; kvb++) {
        bf16x8 kf = *(const bf16x8*)(sm + (kvb * 4 + ks) * 1024 + lane * 16);
        sacc[kvb][0] = MFMA(kf, qf[0][ks], sacc[kvb][0]);
        sacc[kvb][1] = MFMA(kf, qf[1][ks], sacc[kvb][1]);
      }

    if (t <= 1 || t >= 8) {  // only window-edge / causal-edge tiles need masks
#pragma unroll
      for (int kvb = 0; kvb < 4; kvb++)
#pragma unroll
        for (int mb = 0; mb < 2; mb++) {
          int qg = q0 + w * 32 + mb * 16 + l15;
          int kgb = kv0 + kvb * 16 + lg * 4;
#pragma unroll
          for (int r = 0; r < 4; r++) {
            int diff = qg - (kgb + r);
            if (diff < 0 || diff > 512) sacc[kvb][mb][r] = -1e30f;
          }
        }
    }

#pragma unroll
    for (int mb = 0; mb < 2; mb++) {
      float tmax = -1e30f;
#pragma unroll
      for (int kvb = 0; kvb < 4; kvb++)
#pragma unroll
        for (int r = 0; r < 4; r++) tmax = fmaxf(tmax, sacc[kvb][mb][r]);
      tmax = fmaxf(tmax, __shfl_xor(tmax, 16));
      tmax = fmaxf(tmax, __shfl_xor(tmax, 32));
      float mnew = fmaxf(mrun[mb], tmax);
      float alpha = __expf(mrun[mb] - mnew);
      mrun[mb] = mnew;
      float lsum = 0.f;
#pragma unroll
      for (int kvb = 0; kvb < 4; kvb++) {
        u16x4 pk;
#pragma unroll
        for (int r = 0; r < 4; r++) {
          float p = __expf(sacc[kvb][mb][r] - mnew);
          lsum += p;
          pk[r] = f2bf(p);
        }
        *(u16x4*)(Ps + (mb * 16 + l15) * 144 + kvb * 32 + lg * 8) = pk;
      }
      lsum += __shfl_xor(lsum, 16);
      lsum += __shfl_xor(lsum, 32);
      lrun[mb] = lrun[mb] * alpha + lsum;
#pragma unroll
      for (int db = 0; db < 8; db++)
#pragma unroll
        for (int r = 0; r < 4; r++) oacc[db][mb][r] *= alpha;
    }

    // O^T += V^T · P^T  (A = V^T frag, lane-linear; B = P^T, contiguous b128)
#pragma unroll
    for (int kvs = 0; kvs < 2; kvs++) {
      bf16x8 pf0 = *(const bf16x8*)(Ps + (0 + l15) * 144 + kvs * 64 + lg * 16);
      bf16x8 pf1 = *(const bf16x8*)(Ps + (16 + l15) * 144 + kvs * 64 + lg * 16);
#pragma unroll
      for (int db = 0; db < 8; db++) {
        bf16x8 vf = *(const bf16x8*)(sm + 16384 + (db * 2 + kvs) * 1024 + lane * 16);
        oacc[db][0] = MFMA(vf, pf0, oacc[db][0]);
        oacc[db][1] = MFMA(vf, pf1, oacc[db][1]);
      }
    }
  }

#pragma unroll
  for (int mb = 0; mb < 2; mb++) {
    float inv = 1.0f / lrun[mb];
    int s = q0 + w * 32 + mb * 16 + l15;
    unsigned short* orow = O + (size_t)(b * 4096 + s) * 2048 + h * 128 + lg * 4;
#pragma unroll
    for (int db = 0; db < 8; db++) {
      u16x4 pk;
#pragma unroll
      for (int r = 0; r < 4; r++) pk[r] = f2bf(oacc[db][mb][r] * inv);
      *(u16x4*)(orow + db * 16) = pk;
    }
  }
}

// ---------------------------------------------------------------------------
extern "C" void kernel_launch(void* const* d_in, const int* in_sizes, int n_in,
                              void* d_out, int out_size, void* d_ws, size_t ws_size,
                              hipStream_t stream) {
  const float* x = (const float*)d_in[0];       // [2,4096,2048]
  const float* w_qkv = (const float*)d_in[1];   // [6144,2048]
  const float* w_out = (const float*)d_in[2];   // [2048,2048]
  float* out = (float*)d_out;                   // [2,4096,2048] fp32

  char* ws = (char*)d_ws;
  unsigned short* XB    = (unsigned short*)(ws);                         // 32M
  unsigned short* WQKVB = (unsigned short*)(ws + 33554432);              // 24M
  unsigned short* WOUTB = (unsigned short*)(ws + 58720256);              // 8M
  unsigned short* QKb   = (unsigned short*)(ws + 67108864);              // 64M
  unsigned short* VTb   = (unsigned short*)(ws + 134217728);             // 32M
  unsigned short* OB    = XB;  // XB dead after GEMM1; reuse for attention output
  // total workspace: 160 MiB

  cast_bf16<<<16384, 256, 0, stream>>>((const float4*)x, (u16x4*)XB, 4194304);
  cast_bf16<<<12288, 256, 0, stream>>>((const float4*)w_qkv, (u16x4*)WQKVB, 3145728);
  cast_bf16<<<4096, 256, 0, stream>>>((const float4*)w_out, (u16x4*)WOUTB, 1048576);

  // qkv = x @ w_qkv^T : M=8192, N=6144, K=2048 ; 256x128 tiles
  gemm_bt<1><<<dim3(32, 48), 512, 0, stream>>>(XB, WQKVB, QKb, VTb, 2048, 0);

  // sliding-window attention: grid = B*H*(S/128)
  attn<<<1024, 256, 0, stream>>>(QKb, VTb, OB);

  // out = o @ w_out^T : M=8192, N=2048, K=2048 ; 256x128 tiles
  gemm_bt<2><<<dim3(32, 16), 512, 0, stream>>>(OB, WOUTB, out, nullptr, 2048, 2048);
}